// Round 1
// baseline (283.617 us; speedup 1.0000x reference)
//
#include <hip/hip_runtime.h>
#include <stdint.h>

#define BSZ 32
#define SEQ 512
#define EMB 512
#define NH  8
#define DKD 64

typedef float f32x4 __attribute__((ext_vector_type(4)));
typedef short s16x8 __attribute__((ext_vector_type(8)));

__device__ inline unsigned short f2bf(float f) {
  union { float f; unsigned u; } v; v.f = f;
  unsigned r = v.u + 0x7fffu + ((v.u >> 16) & 1u);   // RNE
  return (unsigned short)(r >> 16);
}

__device__ inline float wave_max(float v) {
  #pragma unroll
  for (int o = 32; o; o >>= 1) v = fmaxf(v, __shfl_xor(v, o, 64));
  return v;
}
__device__ inline float wave_sum(float v) {
  #pragma unroll
  for (int o = 32; o; o >>= 1) v += __shfl_xor(v, o, 64);
  return v;
}

// C[M][N] = A(f32 MxK) @ B(f32 NxK)^T + bias
// MODE 0: bf16 out, head-split [b,h,s,d]
// MODE 1: bf16 out, head-split transposed [b,h,d,s]
// MODE 2: f32 out, row-major [M][N]
template<int MODE>
__global__ __launch_bounds__(256)
void gemm_bt(const float* __restrict__ A, const float* __restrict__ B,
             const float* __restrict__ bias, void* __restrict__ C,
             int M, int N, int K)
{
  __shared__ __align__(16) unsigned short Al[128 * 40];  // padded: stride 40 bf16
  __shared__ __align__(16) unsigned short Bl[128 * 40];
  const int tid  = threadIdx.x;
  const int lane = tid & 63;
  const int w    = tid >> 6;
  const int m0   = blockIdx.y * 128;
  const int n0   = blockIdx.x * 128;
  const int wr   = (w >> 1) * 64;
  const int wc   = (w & 1) * 64;
  const int srow = tid >> 3;        // 0..31
  const int scol = (tid & 7) * 4;   // 0..28

  f32x4 acc[4][4] = {};

  for (int k0 = 0; k0 < K; k0 += 32) {
    #pragma unroll
    for (int p = 0; p < 4; ++p) {
      const int r = p * 32 + srow;
      float4 va = *reinterpret_cast<const float4*>(&A[(size_t)(m0 + r) * K + k0 + scol]);
      float4 vb = *reinterpret_cast<const float4*>(&B[(size_t)(n0 + r) * K + k0 + scol]);
      *reinterpret_cast<ushort4*>(&Al[r * 40 + scol]) =
          make_ushort4(f2bf(va.x), f2bf(va.y), f2bf(va.z), f2bf(va.w));
      *reinterpret_cast<ushort4*>(&Bl[r * 40 + scol]) =
          make_ushort4(f2bf(vb.x), f2bf(vb.y), f2bf(vb.z), f2bf(vb.w));
    }
    __syncthreads();
    s16x8 af[4], bf[4];
    #pragma unroll
    for (int i = 0; i < 4; ++i)
      af[i] = *reinterpret_cast<const s16x8*>(&Al[(wr + i * 16 + (lane & 15)) * 40 + (lane >> 4) * 8]);
    #pragma unroll
    for (int j = 0; j < 4; ++j)
      bf[j] = *reinterpret_cast<const s16x8*>(&Bl[(wc + j * 16 + (lane & 15)) * 40 + (lane >> 4) * 8]);
    #pragma unroll
    for (int i = 0; i < 4; ++i)
      #pragma unroll
      for (int j = 0; j < 4; ++j)
        acc[i][j] = __builtin_amdgcn_mfma_f32_16x16x32_bf16(af[i], bf[j], acc[i][j], 0, 0, 0);
    __syncthreads();
  }

  #pragma unroll
  for (int i = 0; i < 4; ++i)
    #pragma unroll
    for (int j = 0; j < 4; ++j)
      #pragma unroll
      for (int r = 0; r < 4; ++r) {
        const int gm = m0 + wr + i * 16 + (lane >> 4) * 4 + r;
        const int gn = n0 + wc + j * 16 + (lane & 15);
        const float vv = acc[i][j][r] + bias[gn];
        if (MODE == 2) {
          ((float*)C)[(size_t)gm * N + gn] = vv;
        } else {
          const int b = gm >> 9, s = gm & 511, h = gn >> 6, d = gn & 63;
          const size_t off = (MODE == 0)
              ? ((size_t)(b * NH + h) * SEQ + s) * DKD + d
              : ((size_t)(b * NH + h) * DKD + d) * SEQ + s;
          ((unsigned short*)C)[off] = f2bf(vv);
        }
      }
}

// One WG (4 waves) per (b, h, 16-row q-block).
__global__ __launch_bounds__(256)
void attn_kernel(const unsigned short* __restrict__ Qh,
                 const unsigned short* __restrict__ Kh,
                 const unsigned short* __restrict__ Vt,
                 float* __restrict__ Aout,
                 const float* __restrict__ gammas,
                 const int* __restrict__ zero_pad)
{
  __shared__ __align__(16) float          s_lds[16 * 512];   // raw scores (scaled)
  __shared__ __align__(16) unsigned short p_lds[16 * 512];   // P (bf16), XOR-swizzled
  const int tid = threadIdx.x, lane = tid & 63, w = tid >> 6;
  const int qb = blockIdx.x, h = blockIdx.y, b = blockIdx.z;
  const size_t bh = (size_t)b * NH + h;
  const unsigned short* Qp = Qh + bh * SEQ * DKD;
  const unsigned short* Kp = Kh + bh * SEQ * DKD;
  const unsigned short* Vp = Vt + bh * DKD * SEQ;
  const int q0 = qb * 16;

  // ---- phase 1: S = Q[q0:q0+16] @ K^T * (1/8) -> s_lds[16][512]
  s16x8 aq[2];
  #pragma unroll
  for (int kt = 0; kt < 2; ++kt)
    aq[kt] = *reinterpret_cast<const s16x8*>(&Qp[(q0 + (lane & 15)) * DKD + kt * 32 + (lane >> 4) * 8]);
  const int c0 = w * 128;
  #pragma unroll
  for (int nt = 0; nt < 8; ++nt) {
    f32x4 acc = {};
    const int n = c0 + nt * 16 + (lane & 15);
    #pragma unroll
    for (int kt = 0; kt < 2; ++kt) {
      s16x8 bk = *reinterpret_cast<const s16x8*>(&Kp[n * DKD + kt * 32 + (lane >> 4) * 8]);
      acc = __builtin_amdgcn_mfma_f32_16x16x32_bf16(aq[kt], bk, acc, 0, 0, 0);
    }
    #pragma unroll
    for (int r = 0; r < 4; ++r)
      s_lds[((lane >> 4) * 4 + r) * 512 + n] = acc[r] * 0.125f;
  }
  __syncthreads();

  // ---- phase 2: per-row softmax -> cumsum -> decay -> softmax2 -> P (bf16)
  const float gamma = -log1pf(__expf(gammas[h]));  // -softplus(g)
  const int zp = zero_pad[0];
  for (int rr = 0; rr < 4; ++rr) {
    const int r  = w * 4 + rr;
    const int qg = q0 + r;          // global q row; valid cols are j < qg
    float s[8];
    {
      float4 v0 = *reinterpret_cast<const float4*>(&s_lds[r * 512 + lane * 8]);
      float4 v1 = *reinterpret_cast<const float4*>(&s_lds[r * 512 + lane * 8 + 4]);
      s[0]=v0.x; s[1]=v0.y; s[2]=v0.z; s[3]=v0.w;
      s[4]=v1.x; s[5]=v1.y; s[6]=v1.z; s[7]=v1.w;
    }
    float pn2[8];
    if (qg == 0) {
      const float u = zp ? 0.0f : (1.0f / 512.0f);
      #pragma unroll
      for (int i = 0; i < 8; ++i) pn2[i] = u;
    } else {
      const int jb = lane * 8;
      float m = -__builtin_inff();
      #pragma unroll
      for (int i = 0; i < 8; ++i) if (jb + i < qg) m = fmaxf(m, s[i]);
      m = wave_max(m);
      float p[8];
      #pragma unroll
      for (int i = 0; i < 8; ++i) p[i] = (jb + i < qg) ? __expf(s[i] - m) : 0.f;
      const float tot = wave_sum(p[0]+p[1]+p[2]+p[3]+p[4]+p[5]+p[6]+p[7]);
      const float inv = 1.0f / tot;
      float c[8]; float run = 0.f;
      #pragma unroll
      for (int i = 0; i < 8; ++i) { p[i] *= inv; run += p[i]; c[i] = run; }
      float t = run;                       // inclusive wave scan of lane totals
      #pragma unroll
      for (int o = 1; o < 64; o <<= 1) { float u = __shfl_up(t, o, 64); if (lane >= o) t += u; }
      const float excl = t - run;
      const float dtot = __shfl(t, 63, 64);  // == reference disttotal (~1)
      float s2[8];
      #pragma unroll
      for (int i = 0; i < 8; ++i) {
        const int j = jb + i;
        if (j < qg) {
          const float rem  = dtot - (c[i] + excl);
          const float prod = rem * (float)(qg - j);
          const float d    = sqrtf(fmaxf(prod, 0.f));
          float te = __expf(d * gamma);
          te = fminf(fmaxf(te, 1e-5f), 1e5f);
          s2[i] = s[i] * te;
        } else s2[i] = -__builtin_inff();
      }
      float m2 = -__builtin_inff();
      #pragma unroll
      for (int i = 0; i < 8; ++i) m2 = fmaxf(m2, s2[i]);
      m2 = wave_max(m2);
      float p2[8];
      #pragma unroll
      for (int i = 0; i < 8; ++i) p2[i] = (jb + i < qg) ? __expf(s2[i] - m2) : 0.f;
      const float inv2 = 1.0f / wave_sum(p2[0]+p2[1]+p2[2]+p2[3]+p2[4]+p2[5]+p2[6]+p2[7]);
      #pragma unroll
      for (int i = 0; i < 8; ++i) pn2[i] = p2[i] * inv2;
    }
    // store P row, 16B per lane, XOR-swizzled granule (both-sides swizzle with phase 3)
    uint4 pw;
    pw.x = (unsigned)f2bf(pn2[0]) | ((unsigned)f2bf(pn2[1]) << 16);
    pw.y = (unsigned)f2bf(pn2[2]) | ((unsigned)f2bf(pn2[3]) << 16);
    pw.z = (unsigned)f2bf(pn2[4]) | ((unsigned)f2bf(pn2[5]) << 16);
    pw.w = (unsigned)f2bf(pn2[6]) | ((unsigned)f2bf(pn2[7]) << 16);
    const int gs = lane ^ (r & 7);
    *reinterpret_cast<uint4*>(reinterpret_cast<char*>(p_lds) + r * 1024 + gs * 16) = pw;
  }
  __syncthreads();

  // ---- phase 3: out = P @ V (V stored transposed [d][s]); wave w -> d cols [w*16, w*16+16)
  f32x4 oacc = {};
  #pragma unroll
  for (int ks = 0; ks < 16; ++ks) {
    const int row = lane & 15;
    const int g   = ks * 4 + (lane >> 4);
    const int gsw = g ^ (row & 7);
    s16x8 pa = *reinterpret_cast<const s16x8*>(reinterpret_cast<const char*>(p_lds) + row * 1024 + gsw * 16);
    s16x8 vb = *reinterpret_cast<const s16x8*>(&Vp[(w * 16 + (lane & 15)) * SEQ + ks * 32 + (lane >> 4) * 8]);
    oacc = __builtin_amdgcn_mfma_f32_16x16x32_bf16(pa, vb, oacc, 0, 0, 0);
  }
  #pragma unroll
  for (int r = 0; r < 4; ++r) {
    const int row = (lane >> 4) * 4 + r;
    const int col = w * 16 + (lane & 15);
    Aout[((size_t)b * SEQ + (q0 + row)) * EMB + h * DKD + col] = oacc[r];
  }
}

extern "C" void kernel_launch(void* const* d_in, const int* in_sizes, int n_in,
                              void* d_out, int out_size, void* d_ws, size_t ws_size,
                              hipStream_t stream)
{
  const float* q  = (const float*)d_in[0];
  const float* k  = (const float*)d_in[1];
  const float* v  = (const float*)d_in[2];
  // d_in[3] = mask (strictly causal, computed analytically on device)
  const int*   zp = (const int*)d_in[4];
  const float* Wq = (const float*)d_in[5];
  const float* bq = (const float*)d_in[6];
  const float* Wk = (const float*)d_in[7];
  const float* bk = (const float*)d_in[8];
  const float* Wv = (const float*)d_in[9];
  const float* bv = (const float*)d_in[10];
  const float* Wo = (const float*)d_in[11];
  const float* bo = (const float*)d_in[12];
  const float* gm = (const float*)d_in[13];

  char* ws = (char*)d_ws;
  const size_t HB = (size_t)BSZ * NH * SEQ * DKD * sizeof(unsigned short); // 16 MiB
  unsigned short* Qh = (unsigned short*)(ws);
  unsigned short* Kh = (unsigned short*)(ws + HB);
  unsigned short* Vt = (unsigned short*)(ws + 2 * HB);
  float*          At = (float*)(ws + 3 * HB);

  const int M = BSZ * SEQ, N = EMB, K = EMB;
  dim3 ggrid(N / 128, M / 128);
  gemm_bt<0><<<ggrid, 256, 0, stream>>>(q, Wq, bq, Qh, M, N, K);
  gemm_bt<0><<<ggrid, 256, 0, stream>>>(k, Wk, bk, Kh, M, N, K);
  gemm_bt<1><<<ggrid, 256, 0, stream>>>(v, Wv, bv, Vt, M, N, K);
  attn_kernel<<<dim3(SEQ / 16, NH, BSZ), 256, 0, stream>>>(Qh, Kh, Vt, At, gm, zp);
  gemm_bt<2><<<ggrid, 256, 0, stream>>>(At, Wo, bo, d_out, M, N, K);
}

// Round 2
// 241.395 us; speedup vs baseline: 1.1749x; 1.1749x over previous
//
#include <hip/hip_runtime.h>
#include <stdint.h>

#define BSZ 32
#define SEQ 512
#define EMB 512
#define NH  8
#define DKD 64
#define LOG2E 1.4426950408889634f

typedef float f32x4 __attribute__((ext_vector_type(4)));
typedef short s16x8 __attribute__((ext_vector_type(8)));

#if __has_builtin(__builtin_amdgcn_exp2f)
#define EXP2(x) __builtin_amdgcn_exp2f(x)
#else
#define EXP2(x) exp2f(x)
#endif
#define RCP(x) __builtin_amdgcn_rcpf(x)

__device__ inline unsigned short f2bf(float f) {
  union { float f; unsigned u; } v; v.f = f;
  unsigned r = v.u + 0x7fffu + ((v.u >> 16) & 1u);   // RNE
  return (unsigned short)(r >> 16);
}

__device__ inline float wave_sum(float v) {
  #pragma unroll
  for (int o = 32; o; o >>= 1) v += __shfl_xor(v, o, 64);
  return v;
}

// C[M][N] = (A(f32 MxK) @ B(f32 NxK)^T + bias) * oscale
// MODE 0: bf16 out, head-split [b,h,s,d]
// MODE 1: bf16 out, head-split transposed [b,h,d,s]
// MODE 2: f32 out, row-major [M][N]
template<int MODE>
__global__ __launch_bounds__(256)
void gemm_bt(const float* __restrict__ A, const float* __restrict__ B,
             const float* __restrict__ bias, void* __restrict__ C,
             int M, int N, int K, float oscale)
{
  __shared__ __align__(16) unsigned short Al[128 * 40];  // padded: stride 40 bf16
  __shared__ __align__(16) unsigned short Bl[128 * 40];
  const int tid  = threadIdx.x;
  const int lane = tid & 63;
  const int w    = tid >> 6;
  const int m0   = blockIdx.y * 128;
  const int n0   = blockIdx.x * 128;
  const int wr   = (w >> 1) * 64;
  const int wc   = (w & 1) * 64;
  const int srow = tid >> 3;        // 0..31
  const int scol = (tid & 7) * 4;   // 0..28

  f32x4 acc[4][4] = {};

  for (int k0 = 0; k0 < K; k0 += 32) {
    #pragma unroll
    for (int p = 0; p < 4; ++p) {
      const int r = p * 32 + srow;
      float4 va = *reinterpret_cast<const float4*>(&A[(size_t)(m0 + r) * K + k0 + scol]);
      float4 vb = *reinterpret_cast<const float4*>(&B[(size_t)(n0 + r) * K + k0 + scol]);
      *reinterpret_cast<ushort4*>(&Al[r * 40 + scol]) =
          make_ushort4(f2bf(va.x), f2bf(va.y), f2bf(va.z), f2bf(va.w));
      *reinterpret_cast<ushort4*>(&Bl[r * 40 + scol]) =
          make_ushort4(f2bf(vb.x), f2bf(vb.y), f2bf(vb.z), f2bf(vb.w));
    }
    __syncthreads();
    s16x8 af[4], bf[4];
    #pragma unroll
    for (int i = 0; i < 4; ++i)
      af[i] = *reinterpret_cast<const s16x8*>(&Al[(wr + i * 16 + (lane & 15)) * 40 + (lane >> 4) * 8]);
    #pragma unroll
    for (int j = 0; j < 4; ++j)
      bf[j] = *reinterpret_cast<const s16x8*>(&Bl[(wc + j * 16 + (lane & 15)) * 40 + (lane >> 4) * 8]);
    #pragma unroll
    for (int i = 0; i < 4; ++i)
      #pragma unroll
      for (int j = 0; j < 4; ++j)
        acc[i][j] = __builtin_amdgcn_mfma_f32_16x16x32_bf16(af[i], bf[j], acc[i][j], 0, 0, 0);
    __syncthreads();
  }

  #pragma unroll
  for (int i = 0; i < 4; ++i)
    #pragma unroll
    for (int j = 0; j < 4; ++j)
      #pragma unroll
      for (int r = 0; r < 4; ++r) {
        const int gm = m0 + wr + i * 16 + (lane >> 4) * 4 + r;
        const int gn = n0 + wc + j * 16 + (lane & 15);
        const float vv = (acc[i][j][r] + bias[gn]) * oscale;
        if (MODE == 2) {
          ((float*)C)[(size_t)gm * N + gn] = vv;
        } else {
          const int b = gm >> 9, s = gm & 511, h = gn >> 6, d = gn & 63;
          const size_t off = (MODE == 0)
              ? ((size_t)(b * NH + h) * SEQ + s) * DKD + d
              : ((size_t)(b * NH + h) * DKD + d) * SEQ + s;
          ((unsigned short*)C)[off] = f2bf(vv);
        }
      }
}

// One WG (4 waves) per (b, h, 16-row q-block).
// LDS: single 32 KB buffer; f32 scores [16][512] (2 KB/row); the bf16 P row
// (1 KB) is overlaid onto the first half of each score row after the row is
// fully register-resident in phase 2.
__global__ __launch_bounds__(256)
void attn_kernel(const unsigned short* __restrict__ Qh,
                 const unsigned short* __restrict__ Kh,
                 const unsigned short* __restrict__ Vt,
                 float* __restrict__ Aout,
                 const float* __restrict__ gammas,
                 const int* __restrict__ zero_pad)
{
  __shared__ __align__(16) float s_lds[16 * 512];   // 32 KB
  char* const s_bytes = reinterpret_cast<char*>(s_lds);
  const int tid = threadIdx.x, lane = tid & 63, w = tid >> 6;
  const int qb = blockIdx.x, h = blockIdx.y, b = blockIdx.z;
  const size_t bh = (size_t)b * NH + h;
  const unsigned short* Qp = Qh + bh * SEQ * DKD;
  const unsigned short* Kp = Kh + bh * SEQ * DKD;
  const unsigned short* Vp = Vt + bh * DKD * SEQ;
  const int q0 = qb * 16;

  // ---- phase 1: S = Qs[q0:q0+16] @ K^T  (Q already scaled by 1/8 at projection)
  s16x8 aq[2];
  #pragma unroll
  for (int kt = 0; kt < 2; ++kt)
    aq[kt] = *reinterpret_cast<const s16x8*>(&Qp[(q0 + (lane & 15)) * DKD + kt * 32 + (lane >> 4) * 8]);
  const int c0 = w * 128;
  #pragma unroll
  for (int nt = 0; nt < 8; ++nt) {
    f32x4 acc = {};
    const int n = c0 + nt * 16 + (lane & 15);
    #pragma unroll
    for (int kt = 0; kt < 2; ++kt) {
      s16x8 bk = *reinterpret_cast<const s16x8*>(&Kp[n * DKD + kt * 32 + (lane >> 4) * 8]);
      acc = __builtin_amdgcn_mfma_f32_16x16x32_bf16(aq[kt], bk, acc, 0, 0, 0);
    }
    #pragma unroll
    for (int r = 0; r < 4; ++r)
      s_lds[((lane >> 4) * 4 + r) * 512 + n] = acc[r];
  }
  __syncthreads();

  // ---- phase 2: softmax -> cumsum -> decay -> softmax2 -> bf16 P (overlaid)
  const float g2 = -log1pf(__expf(gammas[h])) * LOG2E;  // -softplus(g) * log2(e)
  const int zp = zero_pad[0];
  const float NEGINF = -__builtin_inff();
  for (int rr = 0; rr < 4; ++rr) {
    const int r  = w * 4 + rr;
    const int qg = q0 + r;          // valid cols are j < qg
    float sL[8];
    {
      float4 v0 = *reinterpret_cast<const float4*>(&s_lds[r * 512 + lane * 8]);
      float4 v1 = *reinterpret_cast<const float4*>(&s_lds[r * 512 + lane * 8 + 4]);
      sL[0]=v0.x; sL[1]=v0.y; sL[2]=v0.z; sL[3]=v0.w;
      sL[4]=v1.x; sL[5]=v1.y; sL[6]=v1.z; sL[7]=v1.w;
    }
    float pn2[8];
    const int jb = lane * 8;
    if (qg == 0) {
      const float u = zp ? 0.0f : (1.0f / 512.0f);
      #pragma unroll
      for (int i = 0; i < 8; ++i) pn2[i] = u;
    } else {
      // single mask application; everything downstream needs no predication
      #pragma unroll
      for (int i = 0; i < 8; ++i) sL[i] = (jb + i < qg) ? sL[i] * LOG2E : NEGINF;
      float p[8], c[8];
      float run = 0.f;
      #pragma unroll
      for (int i = 0; i < 8; ++i) { p[i] = EXP2(sL[i]); run += p[i]; c[i] = run; }
      float t = run;                       // inclusive wave scan of lane totals
      #pragma unroll
      for (int o = 1; o < 64; o <<= 1) { float u = __shfl_up(t, o, 64); if (lane >= o) t += u; }
      const float tot  = __shfl(t, 63, 64);   // row sum (unnormalized)
      const float pre  = tot - (t - run);     // tot - exclusive_prefix(lane)
      const float itot = RCP(tot);
      const float fb   = (float)(qg - jb);
      float p2[8]; float run2 = 0.f;
      #pragma unroll
      for (int i = 0; i < 8; ++i) {
        const float rem = pre - c[i];                       // unnormalized remainder
        const float arg = fmaxf(rem * itot * (fb - (float)i), 0.f);
        float te = EXP2(__builtin_amdgcn_sqrtf(arg) * g2);  // <= 1
        te = fmaxf(te, 1e-5f);
        p2[i] = EXP2(sL[i] * te);                           // masked: -inf*1 -> 0
        run2 += p2[i];
      }
      const float inv2 = RCP(wave_sum(run2));
      #pragma unroll
      for (int i = 0; i < 8; ++i) pn2[i] = p2[i] * inv2;
    }
    // store P row (bf16), 16B per lane, XOR-swizzled granule, overlaid on s row
    uint4 pw;
    pw.x = (unsigned)f2bf(pn2[0]) | ((unsigned)f2bf(pn2[1]) << 16);
    pw.y = (unsigned)f2bf(pn2[2]) | ((unsigned)f2bf(pn2[3]) << 16);
    pw.z = (unsigned)f2bf(pn2[4]) | ((unsigned)f2bf(pn2[5]) << 16);
    pw.w = (unsigned)f2bf(pn2[6]) | ((unsigned)f2bf(pn2[7]) << 16);
    const int gs = lane ^ (r & 7);
    *reinterpret_cast<uint4*>(s_bytes + r * 2048 + gs * 16) = pw;
  }
  __syncthreads();

  // ---- phase 3: out = P @ V (V stored transposed [d][s]); wave w -> d cols [w*16, w*16+16)
  f32x4 oacc = {};
  #pragma unroll
  for (int ks = 0; ks < 16; ++ks) {
    const int row = lane & 15;
    const int g   = ks * 4 + (lane >> 4);
    const int gsw = g ^ (row & 7);
    s16x8 pa = *reinterpret_cast<const s16x8*>(s_bytes + row * 2048 + gsw * 16);
    s16x8 vb = *reinterpret_cast<const s16x8*>(&Vp[(w * 16 + (lane & 15)) * SEQ + ks * 32 + (lane >> 4) * 8]);
    oacc = __builtin_amdgcn_mfma_f32_16x16x32_bf16(pa, vb, oacc, 0, 0, 0);
  }
  #pragma unroll
  for (int r = 0; r < 4; ++r) {
    const int row = (lane >> 4) * 4 + r;
    const int col = w * 16 + (lane & 15);
    Aout[((size_t)b * SEQ + (q0 + row)) * EMB + h * DKD + col] = oacc[r];
  }
}

extern "C" void kernel_launch(void* const* d_in, const int* in_sizes, int n_in,
                              void* d_out, int out_size, void* d_ws, size_t ws_size,
                              hipStream_t stream)
{
  const float* q  = (const float*)d_in[0];
  const float* k  = (const float*)d_in[1];
  const float* v  = (const float*)d_in[2];
  // d_in[3] = mask (strictly causal, computed analytically on device)
  const int*   zp = (const int*)d_in[4];
  const float* Wq = (const float*)d_in[5];
  const float* bq = (const float*)d_in[6];
  const float* Wk = (const float*)d_in[7];
  const float* bk = (const float*)d_in[8];
  const float* Wv = (const float*)d_in[9];
  const float* bv = (const float*)d_in[10];
  const float* Wo = (const float*)d_in[11];
  const float* bo = (const float*)d_in[12];
  const float* gm = (const float*)d_in[13];

  char* ws = (char*)d_ws;
  const size_t HB = (size_t)BSZ * NH * SEQ * DKD * sizeof(unsigned short); // 16 MiB
  unsigned short* Qh = (unsigned short*)(ws);
  unsigned short* Kh = (unsigned short*)(ws + HB);
  unsigned short* Vt = (unsigned short*)(ws + 2 * HB);
  float*          At = (float*)(ws + 3 * HB);

  const int M = BSZ * SEQ, N = EMB, K = EMB;
  dim3 ggrid(N / 128, M / 128);
  gemm_bt<0><<<ggrid, 256, 0, stream>>>(q, Wq, bq, Qh, M, N, K, 0.125f);
  gemm_bt<0><<<ggrid, 256, 0, stream>>>(k, Wk, bk, Kh, M, N, K, 1.0f);
  gemm_bt<1><<<ggrid, 256, 0, stream>>>(v, Wv, bv, Vt, M, N, K, 1.0f);
  attn_kernel<<<dim3(SEQ / 16, NH, BSZ), 256, 0, stream>>>(Qh, Kh, Vt, At, gm, zp);
  gemm_bt<2><<<ggrid, 256, 0, stream>>>(At, Wo, bo, d_out, M, N, K, 1.0f);
}